// Round 8
// baseline (814.910 us; speedup 1.0000x reference)
//
#include <hip/hip_runtime.h>
#include <math.h>

// Problem constants (from reference)
#define NN 50000
#define EG 600000
#define EK 500000
#define H 128
#define INF 64
#define NB 196     // ceil(NN/256) coarse dst-buckets for CSR build

#define GRID 512   // 2 blocks/CU * 256 CUs; LDS 64KB/block -> exactly resident

struct Theta9 { float t[9]; };  // t[i*3+k] = THETAS[i][k]

// ---------------------------------------------------------------- utilities
__device__ __forceinline__ float f4_at(const float4& v, int i) {
  return i == 0 ? v.x : i == 1 ? v.y : i == 2 ? v.z : v.w;
}
__device__ __forceinline__ void fma4(float4& a, float s, const float4& w) {
  a.x += s * w.x; a.y += s * w.y; a.z += s * w.z; a.w += s * w.w;
}
__device__ __forceinline__ float4 relu4(float4 a) {
  a.x = fmaxf(a.x, 0.f); a.y = fmaxf(a.y, 0.f);
  a.z = fmaxf(a.z, 0.f); a.w = fmaxf(a.w, 0.f);
  return a;
}
__device__ __forceinline__ float fast_tanh(float x) {
  float a = fabsf(x);
  float t = __expf(-2.f * a);
  float r = (1.f - t) * __builtin_amdgcn_rcpf(1.f + t);
  return copysignf(r, x);
}
__device__ __forceinline__ float dot_tanh4(const float4& w2, const float4& a) {
  return w2.x * fast_tanh(a.x) + w2.y * fast_tanh(a.y) +
         w2.z * fast_tanh(a.z) + w2.w * fast_tanh(a.w);
}

// ================================================================ CSR build v2
// Two-level bucket counting sort (R6, verified): hist -> scan -> partition ->
// per-bucket local CSR (rp, adj, dinv).

__global__ __launch_bounds__(256) void k_hist(const int* __restrict__ dg,
    const int* __restrict__ dk, int* __restrict__ cg, int* __restrict__ ck) {
  __shared__ int h[512];
  int t = threadIdx.x;
  h[t] = 0; h[t + 256] = 0;
  __syncthreads();
  for (int e = blockIdx.x * 256 + t; e < EG; e += gridDim.x * 256) {
    atomicAdd(&h[dg[e] >> 8], 1);
    if (e < EK) atomicAdd(&h[256 + (dk[e] >> 8)], 1);
  }
  __syncthreads();
  if (t < NB) {
    if (h[t]) atomicAdd(&cg[t], h[t]);
    if (h[256 + t]) atomicAdd(&ck[t], h[256 + t]);
  }
}

__global__ __launch_bounds__(256) void k_bscan(const int* __restrict__ cg,
    const int* __restrict__ ck, int* __restrict__ bg, int* __restrict__ bk,
    int* __restrict__ curg, int* __restrict__ curk,
    int* __restrict__ rpg, int* __restrict__ rpk) {
  __shared__ int sg[256], sk[256];
  int t = threadIdx.x;
  int vg = (t < NB) ? cg[t] : 0;
  int vk = (t < NB) ? ck[t] : 0;
  sg[t] = vg; sk[t] = vk;
  __syncthreads();
  for (int d = 1; d < 256; d <<= 1) {
    int ug = (t >= d) ? sg[t - d] : 0;
    int uk = (t >= d) ? sk[t - d] : 0;
    __syncthreads();
    sg[t] += ug; sk[t] += uk;
    __syncthreads();
  }
  int eg = sg[t] - vg, ek = sk[t] - vk;  // exclusive
  if (t < NB) {
    bg[t] = eg; bk[t] = ek;
    curg[t] = eg; curk[t] = ek;
  }
  if (t == NB - 1) {
    bg[NB] = eg + vg; bk[NB] = ek + vk;
    rpg[NN] = eg + vg; rpk[NN] = ek + vk;
  }
}

template<int E>
__global__ __launch_bounds__(256) void k_part(const int* __restrict__ src,
    const int* __restrict__ dst, int* __restrict__ gcur, int2* __restrict__ ebuf) {
  __shared__ int hist[NB], lbase[NB], cur[NB];
  int t = threadIdx.x;
  int CH = (E + gridDim.x - 1) / gridDim.x;
  int b0 = blockIdx.x * CH;
  int b1 = min(E, b0 + CH);
  if (t < NB) hist[t] = 0;
  __syncthreads();
  for (int e = b0 + t; e < b1; e += 256) atomicAdd(&hist[dst[e] >> 8], 1);
  __syncthreads();
  if (t < NB && hist[t]) lbase[t] = atomicAdd(&gcur[t], hist[t]);
  __syncthreads();
  if (t < NB) cur[t] = 0;
  __syncthreads();
  for (int e = b0 + t; e < b1; e += 256) {
    int d = dst[e];
    int b = d >> 8;
    int r = atomicAdd(&cur[b], 1);
    ebuf[lbase[b] + r] = make_int2(src[e], d);
  }
}

__global__ __launch_bounds__(256) void k_bcsr(const int2* __restrict__ ebuf,
    const int* __restrict__ bbase, int* __restrict__ rp, int* __restrict__ adj,
    float* __restrict__ dinv) {
  __shared__ int hist[256], incl[256], cur[256];
  int t = threadIdx.x, b = blockIdx.x;
  int beg = bbase[b], end = bbase[b + 1];
  int node0 = b << 8;
  int nvalid = min(256, NN - node0);
  hist[t] = 0;
  __syncthreads();
  for (int i = beg + t; i < end; i += 256) atomicAdd(&hist[ebuf[i].y - node0], 1);
  __syncthreads();
  incl[t] = hist[t];
  __syncthreads();
  for (int d = 1; d < 256; d <<= 1) {
    int u = (t >= d) ? incl[t - d] : 0;
    __syncthreads();
    incl[t] += u;
    __syncthreads();
  }
  int excl = incl[t] - hist[t];
  if (t < nvalid) {
    rp[node0 + t] = beg + excl;
    int dg = hist[t]; if (dg < 1) dg = 1;
    dinv[node0 + t] = rsqrtf((float)dg);
  }
  cur[t] = 0;
  incl[t] = excl;
  __syncthreads();
  for (int i = beg + t; i < end; i += 256) {
    int2 ed = ebuf[i];
    int d = ed.y - node0;
    int r = atomicAdd(&cur[d], 1);
    adj[beg + incl[d] + r] = ed.x;
  }
}

// ---------------------------------------------------------------- transpose (weights)
__global__ __launch_bounds__(256) void k_transpose(const float* __restrict__ A,
    float* __restrict__ At, int R, int C) {
  int i = blockIdx.x * 256 + threadIdx.x;
  if (i < R * C) {
    int r = i / C, c = i % C;
    At[c * R + r] = A[i];
  }
}

// ---------------------------------------------------------------- combined conv matrices
__global__ __launch_bounds__(256) void k_genmat(const float* __restrict__ diag,
    const float* __restrict__ Wc, const float* __restrict__ W3, Theta9 th,
    float* __restrict__ A, float* __restrict__ B, float* __restrict__ C) {
  int id = blockIdx.x * 256 + threadIdx.x;  // id = k*128 + j
  int k = id >> 7, j = id & 127;
  float a = 0.f, b = 0.f, c = 0.f;
  for (int i = 0; i < 3; i++) {
    float t0 = th.t[i * 3 + 0], t1 = th.t[i * 3 + 1], t2 = th.t[i * 3 + 2];
    float d0 = diag[(i * 3 + 0) * H + k];
    float d1 = diag[(i * 3 + 1) * H + k];
    float d2 = diag[(i * 3 + 2) * H + k];
    float ci = t0 * d0;
    float alpha = t1 + t2;
    float beta  = -((t1 + t2) * d1 + t2 * d2);
    float gamma = t2 * d1 * d2;
    float w3kj = W3[j * 384 + i * H + k];
    if (ci != 0.f) {
      const float* Wi = Wc + i * H * H;
      float g = 0.f;
      for (int m = 0; m < H; m++)
        g += Wi[m * H + k] * W3[j * 384 + i * H + m];
      a += ci * g;
    }
    a += alpha * w3kj;
    b += beta * w3kj;
    c += gamma * w3kj;
  }
  A[id] = a; B[id] = b; C[id] = c;
}

__global__ __launch_bounds__(256) void k_genbias(const float* __restrict__ bc,
    const float* __restrict__ W3, const float* __restrict__ b3, float* __restrict__ bias) {
  int j = threadIdx.x;
  float s = b3[j];
  for (int i = 0; i < 3; i++)
    for (int m = 0; m < H; m++)
      s += bc[i * H + m] * W3[j * 384 + i * H + m];
  bias[j] = s;
}

// ---------------------------------------------------------------- GEMM helpers
// 7-node balanced tiles: 8192 groups, 7143 tiles, each group <=1 tile (no
// straggler; old grid-stride gave 142 blocks 2x work -> 2x critical path).
__device__ __forceinline__ void accum7(const float* __restrict__ X, int n0, int nv,
    const float* __restrict__ wlds, int lane, float4* a) {
  const float* x0 = X + (size_t)n0 * H;
  if (nv == 7) {
    for (int k = 0; k < H; k += 4) {
      float4 xv[7];
#pragma unroll
      for (int i = 0; i < 7; i++)
        xv[i] = *(const float4*)(x0 + (size_t)i * H + k);
#pragma unroll
      for (int kk = 0; kk < 4; kk++) {
        float4 w = *(const float4*)(wlds + (k + kk) * H + lane * 4);
#pragma unroll
        for (int i = 0; i < 7; i++) fma4(a[i], f4_at(xv[i], kk), w);
      }
    }
  } else {
    for (int k = 0; k < H; k += 4) {
      float4 xv[7];
#pragma unroll
      for (int i = 0; i < 7; i++)
        xv[i] = (i < nv) ? *(const float4*)(x0 + (size_t)i * H + k)
                         : make_float4(0.f, 0.f, 0.f, 0.f);
#pragma unroll
      for (int kk = 0; kk < 4; kk++) {
        float4 w = *(const float4*)(wlds + (k + kk) * H + lane * 4);
#pragma unroll
        for (int i = 0; i < 7; i++) fma4(a[i], f4_at(xv[i], kk), w);
      }
    }
  }
}

// ---------------------------------------------------------------- LDS-weight GEMM
// Y = relu(X[NN x K] * Wt[K x 128] + bias). NPG nodes per 32-lane group,
// exactly one tile per group (balanced).
template<int K, int NPG>
__global__ __launch_bounds__(512) void k_gemm(const float* __restrict__ X,
    const float* __restrict__ Wt, const float* __restrict__ bias,
    float* __restrict__ Y) {
  __shared__ float wlds[K * H];
#pragma unroll
  for (int i = 0; i < K * H / 2048; i++) {
    int idx = (threadIdx.x + i * 512) * 4;
    *(float4*)(wlds + idx) = *(const float4*)(Wt + idx);
  }
  __syncthreads();
  const int lane = threadIdx.x & 31;
  const int g = (threadIdx.x >> 5) * gridDim.x + blockIdx.x;
  const int n0 = g * NPG;
  if (n0 >= NN) return;
  const int nv = min(NPG, NN - n0);
  float4 bb = *(const float4*)(bias + lane * 4);
  float4 a[NPG];
#pragma unroll
  for (int i = 0; i < NPG; i++) a[i] = bb;
  const float* x0 = X + (size_t)n0 * K;
  if (nv == NPG) {
    for (int k = 0; k < K; k += 4) {
      float4 xv[NPG];
#pragma unroll
      for (int i = 0; i < NPG; i++)
        xv[i] = *(const float4*)(x0 + (size_t)i * K + k);
#pragma unroll
      for (int kk = 0; kk < 4; kk++) {
        float4 w = *(const float4*)(wlds + (k + kk) * H + lane * 4);
#pragma unroll
        for (int i = 0; i < NPG; i++) fma4(a[i], f4_at(xv[i], kk), w);
      }
    }
  } else {
    for (int k = 0; k < K; k += 4) {
      float4 xv[NPG];
#pragma unroll
      for (int i = 0; i < NPG; i++)
        xv[i] = (i < nv) ? *(const float4*)(x0 + (size_t)i * K + k)
                         : make_float4(0.f, 0.f, 0.f, 0.f);
#pragma unroll
      for (int kk = 0; kk < 4; kk++) {
        float4 w = *(const float4*)(wlds + (k + kk) * H + lane * 4);
#pragma unroll
        for (int i = 0; i < NPG; i++) fma4(a[i], f4_at(xv[i], kk), w);
      }
    }
  }
  float* y = Y + (size_t)n0 * H + lane * 4;
#pragma unroll
  for (int i = 0; i < NPG; i++)
    if (i < nv) *(float4*)(y + (size_t)i * H) = relu4(a[i]);
}

// ---------------------------------------------------------------- fused 3-phase conv GEMM
// Y = relu(X0*A + X1*B + X2*C + bias); acc in VGPRs across phases, A/B/C
// rotate through LDS. One balanced 7-node tile per group.
__global__ __launch_bounds__(512) void k_lin3f(const float* __restrict__ X0,
    const float* __restrict__ X1, const float* __restrict__ X2,
    const float* __restrict__ A, const float* __restrict__ B,
    const float* __restrict__ C, const float* __restrict__ bias,
    float* __restrict__ Y) {
  __shared__ float wlds[H * H];
  const int lane = threadIdx.x & 31;
  const int g = (threadIdx.x >> 5) * gridDim.x + blockIdx.x;
  const int n0 = g * 7;
  const int nv = (n0 < NN) ? min(7, NN - n0) : 0;
  float4 bb = *(const float4*)(bias + lane * 4);
  float4 a[7];
#pragma unroll
  for (int i = 0; i < 7; i++) a[i] = bb;

#define PHASE(W, X)                                                      \
  {                                                                      \
    __syncthreads();                                                     \
    _Pragma("unroll")                                                    \
    for (int i = 0; i < 8; i++) {                                        \
      int idx = (threadIdx.x + i * 512) * 4;                             \
      *(float4*)(wlds + idx) = *(const float4*)((W) + idx);              \
    }                                                                    \
    __syncthreads();                                                     \
    if (nv) accum7((X), n0, nv, wlds, lane, a);                          \
  }

  PHASE(A, X0)
  PHASE(B, X1)
  PHASE(C, X2)
#undef PHASE

  if (nv) {
    float* y = Y + (size_t)n0 * H + lane * 4;
#pragma unroll
    for (int i = 0; i < 7; i++)
      if (i < nv) *(float4*)(y + (size_t)i * H) = relu4(a[i]);
  }
}

// ---------------------------------------------------------------- attention
// 7-node balanced tile; two sequential stream passes (o then k) to halve
// live VGPRs. Wave reduce -> LDS partials -> 2 atomics/block.
__global__ __launch_bounds__(512) void k_attn(const float* __restrict__ Ho,
    const float* __restrict__ Hk, const float* __restrict__ Wa1t,
    const float* __restrict__ ba1, const float* __restrict__ Wa2,
    float* __restrict__ sums) {
  __shared__ float wlds[H * H];
#pragma unroll
  for (int i = 0; i < 8; i++) {
    int idx = (threadIdx.x + i * 512) * 4;
    *(float4*)(wlds + idx) = *(const float4*)(Wa1t + idx);
  }
  __syncthreads();
  const int lane = threadIdx.x & 31;
  const int g = (threadIdx.x >> 5) * gridDim.x + blockIdx.x;
  const int n0 = g * 7;
  float po = 0.f, pk = 0.f;
  if (n0 < NN) {
    const int nv = min(7, NN - n0);
    float4 bb = *(const float4*)(ba1 + lane * 4);
    float4 w2 = *(const float4*)(Wa2 + lane * 4);
    {
      float4 a[7];
#pragma unroll
      for (int i = 0; i < 7; i++) a[i] = bb;
      accum7(Ho, n0, nv, wlds, lane, a);
#pragma unroll
      for (int i = 0; i < 7; i++)
        if (i < nv) po += dot_tanh4(w2, a[i]);
    }
    {
      float4 a[7];
#pragma unroll
      for (int i = 0; i < 7; i++) a[i] = bb;
      accum7(Hk, n0, nv, wlds, lane, a);
#pragma unroll
      for (int i = 0; i < 7; i++)
        if (i < nv) pk += dot_tanh4(w2, a[i]);
    }
  }
  for (int d = 32; d > 0; d >>= 1) {
    po += __shfl_down(po, d, 64);
    pk += __shfl_down(pk, d, 64);
  }
  __syncthreads();  // all weight reads done; safe to reuse wlds
  int wv = threadIdx.x >> 6;
  if ((threadIdx.x & 63) == 0) { wlds[wv] = po; wlds[8 + wv] = pk; }
  __syncthreads();
  if (threadIdx.x == 0) {
    float so = 0.f, sk = 0.f;
    for (int i = 0; i < 8; i++) { so += wlds[i]; sk += wlds[8 + i]; }
    atomicAdd(&sums[0], so);
    atomicAdd(&sums[1], sk);
  }
}

// ---------------------------------------------------------------- SpMM
// Y[n] = dinv[n] * sum_{s in adj(n)} X[s]*dinv[s]; 8-deep edge unroll
// (8 row-gathers in flight per group; gather-latency bound).
__global__ __launch_bounds__(256) void k_spmm(const float* __restrict__ X,
    const float* __restrict__ dinv, const int* __restrict__ rp,
    const int* __restrict__ adj, float* __restrict__ Y) {
  int g = blockIdx.x * blockDim.x + threadIdx.x;
  int n = g >> 5, lane = g & 31;
  if (n >= NN) return;
  float4 acc = make_float4(0.f, 0.f, 0.f, 0.f);
  int beg = rp[n], end = rp[n + 1];
  const float* Xl = X + lane * 4;
  int e = beg;
  for (; e + 8 <= end; e += 8) {
    int s[8];
#pragma unroll
    for (int j = 0; j < 8; j++) s[j] = adj[e + j];
    float d[8];
#pragma unroll
    for (int j = 0; j < 8; j++) d[j] = dinv[s[j]];
    float4 v[8];
#pragma unroll
    for (int j = 0; j < 8; j++) v[j] = *(const float4*)(Xl + (size_t)s[j] * H);
#pragma unroll
    for (int j = 0; j < 8; j++) fma4(acc, d[j], v[j]);
  }
  for (; e + 4 <= end; e += 4) {
    int s0 = adj[e], s1 = adj[e + 1], s2 = adj[e + 2], s3 = adj[e + 3];
    float d0 = dinv[s0], d1 = dinv[s1], d2 = dinv[s2], d3 = dinv[s3];
    float4 v0 = *(const float4*)(Xl + (size_t)s0 * H);
    float4 v1 = *(const float4*)(Xl + (size_t)s1 * H);
    float4 v2 = *(const float4*)(Xl + (size_t)s2 * H);
    float4 v3 = *(const float4*)(Xl + (size_t)s3 * H);
    fma4(acc, d0, v0);
    fma4(acc, d1, v1);
    fma4(acc, d2, v2);
    fma4(acc, d3, v3);
  }
  for (; e < end; e++) {
    int s = adj[e];
    fma4(acc, dinv[s], *(const float4*)(Xl + (size_t)s * H));
  }
  float dn = dinv[n];
  acc.x *= dn; acc.y *= dn; acc.z *= dn; acc.w *= dn;
  *(float4*)(Y + (size_t)n * H + lane * 4) = acc;
}

// ---------------------------------------------------------------- final: beta-blend + classifier
__global__ __launch_bounds__(256) void k_final(const float* __restrict__ Ho,
    const float* __restrict__ Hk, const float* __restrict__ sums,
    const float* __restrict__ W4, const float* __restrict__ b4,
    float* __restrict__ out) {
  int g = blockIdx.x * blockDim.x + threadIdx.x;
  int n = g >> 5, lane = g & 31;
  if (n >= NN) return;
  float mo = sums[0] * (1.f / NN);
  float mk = sums[1] * (1.f / NN);
  float mx = fmaxf(mo, mk);
  float eo = __expf(mo - mx), ek = __expf(mk - mx);
  float inv = 1.f / (eo + ek);
  float bo = eo * inv, bk2 = ek * inv;
  float4 ho = *(const float4*)(Ho + (size_t)n * H + lane * 4);
  float4 hk = *(const float4*)(Hk + (size_t)n * H + lane * 4);
  float4 emb;
  emb.x = bo * ho.x + bk2 * hk.x;
  emb.y = bo * ho.y + bk2 * hk.y;
  emb.z = bo * ho.z + bk2 * hk.z;
  emb.w = bo * ho.w + bk2 * hk.w;
  *(float4*)(out + 2 * NN + (size_t)n * H + lane * 4) = emb;
  float4 w0 = *(const float4*)(W4 + lane * 4);
  float4 w1 = *(const float4*)(W4 + H + lane * 4);
  float p0 = emb.x * w0.x + emb.y * w0.y + emb.z * w0.z + emb.w * w0.w;
  float p1 = emb.x * w1.x + emb.y * w1.y + emb.z * w1.z + emb.w * w1.w;
  for (int d = 16; d > 0; d >>= 1) {
    p0 += __shfl_down(p0, d, 32);
    p1 += __shfl_down(p1, d, 32);
  }
  if (lane == 0) {
    out[n * 2 + 0] = p0 + b4[0];
    out[n * 2 + 1] = p1 + b4[1];
  }
}

// ================================================================ host
extern "C" void kernel_launch(void* const* d_in, const int* in_sizes, int n_in,
                              void* d_out, int out_size, void* d_ws, size_t ws_size,
                              hipStream_t stream) {
  const float* x      = (const float*)d_in[0];
  const int*   src_g  = (const int*)d_in[1];
  const int*   dst_g  = (const int*)d_in[2];
  const int*   src_k  = (const int*)d_in[3];
  const int*   dst_k  = (const int*)d_in[4];
  const float* W1     = (const float*)d_in[5];
  const float* b1     = (const float*)d_in[6];
  const float* W2     = (const float*)d_in[7];
  const float* b2     = (const float*)d_in[8];
  const float* diag_g = (const float*)d_in[9];
  const float* Wc_g   = (const float*)d_in[10];
  const float* bc_g   = (const float*)d_in[11];
  const float* diag_k = (const float*)d_in[12];
  const float* Wc_k   = (const float*)d_in[13];
  const float* bc_k   = (const float*)d_in[14];
  const float* W3     = (const float*)d_in[15];
  const float* b3     = (const float*)d_in[16];
  const float* Wk     = (const float*)d_in[17];
  const float* bk     = (const float*)d_in[18];
  const float* Wa1    = (const float*)d_in[19];
  const float* ba1    = (const float*)d_in[20];
  const float* Wa2    = (const float*)d_in[21];
  const float* W4     = (const float*)d_in[22];
  const float* b4     = (const float*)d_in[23];
  float* out = (float*)d_out;

  // ---- workspace bump allocator (256B aligned)
  char* base = (char*)d_ws;
  size_t off = 0;
  auto alloc = [&](size_t bytes) -> char* {
    char* r = base + off;
    off = (off + bytes + 255) & ~(size_t)255;
    return r;
  };
  // zero region (memset each launch): bucket counters + sums
  int* bcnt_g = (int*)alloc(256 * 4);
  int* bcnt_k = (int*)alloc(256 * 4);
  float* sums = (float*)alloc(256);
  size_t zero_bytes = off;

  int* bbase_g = (int*)alloc((NB + 1) * 4);
  int* bbase_k = (int*)alloc((NB + 1) * 4);
  int* bcur_g  = (int*)alloc(NB * 4);
  int* bcur_k  = (int*)alloc(NB * 4);
  int* rp_g    = (int*)alloc((NN + 1) * 4);
  int* rp_k    = (int*)alloc((NN + 1) * 4);
  int2* ebuf_g = (int2*)alloc((size_t)EG * 8);
  int2* ebuf_k = (int2*)alloc((size_t)EK * 8);
  int* adj_g   = (int*)alloc(EG * 4);
  int* adj_k   = (int*)alloc(EK * 4);
  float* dinv_g = (float*)alloc(NN * 4);
  float* dinv_k = (float*)alloc(NN * 4);
  float* Wt1  = (float*)alloc(INF * H * 4);
  float* Wt2  = (float*)alloc(H * H * 4);
  float* Wa1t = (float*)alloc(H * H * 4);
  float* Ag = (float*)alloc(H * H * 4);
  float* Bg = (float*)alloc(H * H * 4);
  float* Cg = (float*)alloc(H * H * 4);
  float* biasg = (float*)alloc(H * 4);
  float* Ak = (float*)alloc(H * H * 4);
  float* Bk = (float*)alloc(H * H * 4);
  float* Ck = (float*)alloc(H * H * 4);
  float* biask = (float*)alloc(H * 4);
  float* B0 = (float*)alloc((size_t)NN * H * 4);  // t1, later h_o
  float* B1 = (float*)alloc((size_t)NN * H * 4);  // h
  float* B2 = (float*)alloc((size_t)NN * H * 4);  // u
  float* B3 = (float*)alloc((size_t)NN * H * 4);  // w
  float* B4 = (float*)alloc((size_t)NN * H * 4);  // h_knn
  (void)ws_size; (void)in_sizes; (void)n_in; (void)out_size;

  hipMemsetAsync(d_ws, 0, zero_bytes, stream);

  const int GB = NN * 32 / 256;  // 1 node / 32 threads (spmm, final)

  // CSR build v2: hist -> scan -> partition -> per-bucket CSR (+dinv)
  k_hist<<<512, 256, 0, stream>>>(dst_g, dst_k, bcnt_g, bcnt_k);
  k_bscan<<<1, 256, 0, stream>>>(bcnt_g, bcnt_k, bbase_g, bbase_k,
                                 bcur_g, bcur_k, rp_g, rp_k);
  k_part<EG><<<512, 256, 0, stream>>>(src_g, dst_g, bcur_g, ebuf_g);
  k_part<EK><<<512, 256, 0, stream>>>(src_k, dst_k, bcur_k, ebuf_k);
  k_bcsr<<<NB, 256, 0, stream>>>(ebuf_g, bbase_g, rp_g, adj_g, dinv_g);
  k_bcsr<<<NB, 256, 0, stream>>>(ebuf_k, bbase_k, rp_k, adj_k, dinv_k);

  // weight prep
  k_transpose<<<(H * INF + 255) / 256, 256, 0, stream>>>(W1, Wt1, H, INF);
  k_transpose<<<(H * H + 255) / 256, 256, 0, stream>>>(W2, Wt2, H, H);
  k_transpose<<<(H * H + 255) / 256, 256, 0, stream>>>(Wa1, Wa1t, H, H);
  Theta9 thG = {{3.f, -3.f, 0.75f, 0.f, 3.f, -1.5f, 0.f, 0.f, 0.75f}};
  Theta9 thK = {{1.f, 1.f, 1.f, 1.f, 1.f, 1.f, 1.f, 1.f, 1.f}};
  k_genmat<<<64, 256, 0, stream>>>(diag_g, Wc_g, W3, thG, Ag, Bg, Cg);
  k_genmat<<<64, 256, 0, stream>>>(diag_k, Wc_k, Wk, thK, Ak, Bk, Ck);
  k_genbias<<<1, 128, 0, stream>>>(bc_g, W3, b3, biasg);
  k_genbias<<<1, 128, 0, stream>>>(bc_k, Wk, bk, biask);

  // input MLP: K=64 -> 32KB LDS -> 4 blocks/CU (GRID 1024, 4-node tiles);
  // K=128 -> 64KB LDS -> 2 blocks/CU (GRID 512, 7-node tiles)
  k_gemm<INF, 4><<<1024, 512, 0, stream>>>(x, Wt1, b1, B0);   // t1
  k_gemm<H, 7><<<GRID, 512, 0, stream>>>(B0, Wt2, b2, B1);    // h

  // graph G: u, w, fused conv+fusion (single 3-phase GEMM)
  k_spmm<<<GB, 256, 0, stream>>>(B1, dinv_g, rp_g, adj_g, B2);  // u_g
  k_spmm<<<GB, 256, 0, stream>>>(B2, dinv_g, rp_g, adj_g, B3);  // w_g
  k_lin3f<<<GRID, 512, 0, stream>>>(B1, B2, B3, Ag, Bg, Cg, biasg, B0);  // h_o

  // graph K
  k_spmm<<<GB, 256, 0, stream>>>(B1, dinv_k, rp_k, adj_k, B2);  // u_k
  k_spmm<<<GB, 256, 0, stream>>>(B2, dinv_k, rp_k, adj_k, B3);  // w_k
  k_lin3f<<<GRID, 512, 0, stream>>>(B1, B2, B3, Ak, Bk, Ck, biask, B4);  // h_knn

  // attention + output
  k_attn<<<GRID, 512, 0, stream>>>(B0, B4, Wa1t, ba1, Wa2, sums);
  k_final<<<GB, 256, 0, stream>>>(B0, B4, sums, W4, b4, out);
}

// Round 9
// 684.770 us; speedup vs baseline: 1.1900x; 1.1900x over previous
//
#include <hip/hip_runtime.h>
#include <math.h>

// Problem constants (from reference)
#define NN 50000
#define EG 600000
#define EK 500000
#define H 128
#define INF 64
#define NB 196     // ceil(NN/256) coarse dst-buckets for CSR build

#define GRID 512   // 2 blocks/CU * 256 CUs; LDS 64KB/block -> exactly resident

struct Theta9 { float t[9]; };  // t[i*3+k] = THETAS[i][k]

// ---------------------------------------------------------------- utilities
__device__ __forceinline__ float f4_at(const float4& v, int i) {
  return i == 0 ? v.x : i == 1 ? v.y : i == 2 ? v.z : v.w;
}
__device__ __forceinline__ void fma4(float4& a, float s, const float4& w) {
  a.x += s * w.x; a.y += s * w.y; a.z += s * w.z; a.w += s * w.w;
}
__device__ __forceinline__ float4 relu4(float4 a) {
  a.x = fmaxf(a.x, 0.f); a.y = fmaxf(a.y, 0.f);
  a.z = fmaxf(a.z, 0.f); a.w = fmaxf(a.w, 0.f);
  return a;
}
__device__ __forceinline__ float fast_tanh(float x) {
  float a = fabsf(x);
  float t = __expf(-2.f * a);
  float r = (1.f - t) * __builtin_amdgcn_rcpf(1.f + t);
  return copysignf(r, x);
}
__device__ __forceinline__ float dot_tanh4(const float4& w2, const float4& a) {
  return w2.x * fast_tanh(a.x) + w2.y * fast_tanh(a.y) +
         w2.z * fast_tanh(a.z) + w2.w * fast_tanh(a.w);
}

// ================================================================ CSR build v2
__global__ __launch_bounds__(256) void k_hist(const int* __restrict__ dg,
    const int* __restrict__ dk, int* __restrict__ cg, int* __restrict__ ck) {
  __shared__ int h[512];
  int t = threadIdx.x;
  h[t] = 0; h[t + 256] = 0;
  __syncthreads();
  for (int e = blockIdx.x * 256 + t; e < EG; e += gridDim.x * 256) {
    atomicAdd(&h[dg[e] >> 8], 1);
    if (e < EK) atomicAdd(&h[256 + (dk[e] >> 8)], 1);
  }
  __syncthreads();
  if (t < NB) {
    if (h[t]) atomicAdd(&cg[t], h[t]);
    if (h[256 + t]) atomicAdd(&ck[t], h[256 + t]);
  }
}

__global__ __launch_bounds__(256) void k_bscan(const int* __restrict__ cg,
    const int* __restrict__ ck, int* __restrict__ bg, int* __restrict__ bk,
    int* __restrict__ curg, int* __restrict__ curk,
    int* __restrict__ rpg, int* __restrict__ rpk) {
  __shared__ int sg[256], sk[256];
  int t = threadIdx.x;
  int vg = (t < NB) ? cg[t] : 0;
  int vk = (t < NB) ? ck[t] : 0;
  sg[t] = vg; sk[t] = vk;
  __syncthreads();
  for (int d = 1; d < 256; d <<= 1) {
    int ug = (t >= d) ? sg[t - d] : 0;
    int uk = (t >= d) ? sk[t - d] : 0;
    __syncthreads();
    sg[t] += ug; sk[t] += uk;
    __syncthreads();
  }
  int eg = sg[t] - vg, ek = sk[t] - vk;  // exclusive
  if (t < NB) {
    bg[t] = eg; bk[t] = ek;
    curg[t] = eg; curk[t] = ek;
  }
  if (t == NB - 1) {
    bg[NB] = eg + vg; bk[NB] = ek + vk;
    rpg[NN] = eg + vg; rpk[NN] = ek + vk;
  }
}

template<int E>
__global__ __launch_bounds__(256) void k_part(const int* __restrict__ src,
    const int* __restrict__ dst, int* __restrict__ gcur, int2* __restrict__ ebuf) {
  __shared__ int hist[NB], lbase[NB], cur[NB];
  int t = threadIdx.x;
  int CH = (E + gridDim.x - 1) / gridDim.x;
  int b0 = blockIdx.x * CH;
  int b1 = min(E, b0 + CH);
  if (t < NB) hist[t] = 0;
  __syncthreads();
  for (int e = b0 + t; e < b1; e += 256) atomicAdd(&hist[dst[e] >> 8], 1);
  __syncthreads();
  if (t < NB && hist[t]) lbase[t] = atomicAdd(&gcur[t], hist[t]);
  __syncthreads();
  if (t < NB) cur[t] = 0;
  __syncthreads();
  for (int e = b0 + t; e < b1; e += 256) {
    int d = dst[e];
    int b = d >> 8;
    int r = atomicAdd(&cur[b], 1);
    ebuf[lbase[b] + r] = make_int2(src[e], d);
  }
}

__global__ __launch_bounds__(256) void k_bcsr(const int2* __restrict__ ebuf,
    const int* __restrict__ bbase, int* __restrict__ rp, int* __restrict__ adj,
    float* __restrict__ dinv) {
  __shared__ int hist[256], incl[256], cur[256];
  int t = threadIdx.x, b = blockIdx.x;
  int beg = bbase[b], end = bbase[b + 1];
  int node0 = b << 8;
  int nvalid = min(256, NN - node0);
  hist[t] = 0;
  __syncthreads();
  for (int i = beg + t; i < end; i += 256) atomicAdd(&hist[ebuf[i].y - node0], 1);
  __syncthreads();
  incl[t] = hist[t];
  __syncthreads();
  for (int d = 1; d < 256; d <<= 1) {
    int u = (t >= d) ? incl[t - d] : 0;
    __syncthreads();
    incl[t] += u;
    __syncthreads();
  }
  int excl = incl[t] - hist[t];
  if (t < nvalid) {
    rp[node0 + t] = beg + excl;
    int dg = hist[t]; if (dg < 1) dg = 1;
    dinv[node0 + t] = rsqrtf((float)dg);
  }
  cur[t] = 0;
  incl[t] = excl;
  __syncthreads();
  for (int i = beg + t; i < end; i += 256) {
    int2 ed = ebuf[i];
    int d = ed.y - node0;
    int r = atomicAdd(&cur[d], 1);
    adj[beg + incl[d] + r] = ed.x;
  }
}

// ---------------------------------------------------------------- transpose (weights)
__global__ __launch_bounds__(256) void k_transpose(const float* __restrict__ A,
    float* __restrict__ At, int R, int C) {
  int i = blockIdx.x * 256 + threadIdx.x;
  if (i < R * C) {
    int r = i / C, c = i % C;
    At[c * R + r] = A[i];
  }
}

// ---------------------------------------------------------------- combined conv matrices
__global__ __launch_bounds__(256) void k_genmat(const float* __restrict__ diag,
    const float* __restrict__ Wc, const float* __restrict__ W3, Theta9 th,
    float* __restrict__ A, float* __restrict__ B, float* __restrict__ C) {
  int id = blockIdx.x * 256 + threadIdx.x;  // id = k*128 + j
  int k = id >> 7, j = id & 127;
  float a = 0.f, b = 0.f, c = 0.f;
  for (int i = 0; i < 3; i++) {
    float t0 = th.t[i * 3 + 0], t1 = th.t[i * 3 + 1], t2 = th.t[i * 3 + 2];
    float d0 = diag[(i * 3 + 0) * H + k];
    float d1 = diag[(i * 3 + 1) * H + k];
    float d2 = diag[(i * 3 + 2) * H + k];
    float ci = t0 * d0;
    float alpha = t1 + t2;
    float beta  = -((t1 + t2) * d1 + t2 * d2);
    float gamma = t2 * d1 * d2;
    float w3kj = W3[j * 384 + i * H + k];
    if (ci != 0.f) {
      const float* Wi = Wc + i * H * H;
      float g = 0.f;
      for (int m = 0; m < H; m++)
        g += Wi[m * H + k] * W3[j * 384 + i * H + m];
      a += ci * g;
    }
    a += alpha * w3kj;
    b += beta * w3kj;
    c += gamma * w3kj;
  }
  A[id] = a; B[id] = b; C[id] = c;
}

__global__ __launch_bounds__(256) void k_genbias(const float* __restrict__ bc,
    const float* __restrict__ W3, const float* __restrict__ b3, float* __restrict__ bias) {
  int j = threadIdx.x;
  float s = b3[j];
  for (int i = 0; i < 3; i++)
    for (int m = 0; m < H; m++)
      s += bc[i * H + m] * W3[j * 384 + i * H + m];
  bias[j] = s;
}

// ---------------------------------------------------------------- GEMM tile helper
// 6-node tile, K=128. PREFETCH-1: load iteration k+4's 6 x-rows (xb) while
// FMA-ing iteration k (xa) — hides L2/L3 latency of the group-uniform loads
// (R8 evidence: VALUBusy 24-41%, loads serialized with FMA by compiler).
__device__ __forceinline__ void accum_tile(const float* __restrict__ X, int t,
    const float* __restrict__ wlds, int lane, float4* a) {
  int n0 = t * 6;
  const float* x0 = X + (size_t)n0 * H;
  if (n0 + 6 <= NN) {
    float4 xa[6], xb[6];
#pragma unroll
    for (int i = 0; i < 6; i++) xa[i] = *(const float4*)(x0 + (size_t)i * H);
    for (int k = 0; k < H; k += 4) {
      int kn = (k + 4 < H) ? (k + 4) : k;   // last iter: harmless reload
#pragma unroll
      for (int i = 0; i < 6; i++)
        xb[i] = *(const float4*)(x0 + (size_t)i * H + kn);
#pragma unroll
      for (int kk = 0; kk < 4; kk++) {
        float4 w = *(const float4*)(wlds + (k + kk) * H + lane * 4);
#pragma unroll
        for (int i = 0; i < 6; i++) fma4(a[i], f4_at(xa[i], kk), w);
      }
#pragma unroll
      for (int i = 0; i < 6; i++) xa[i] = xb[i];
    }
  } else {
    int nv = NN - n0;
    for (int k = 0; k < H; k += 4) {
      float4 xv[6];
#pragma unroll
      for (int i = 0; i < 6; i++)
        xv[i] = (i < nv) ? *(const float4*)(x0 + (size_t)i * H + k)
                         : make_float4(0.f, 0.f, 0.f, 0.f);
#pragma unroll
      for (int kk = 0; kk < 4; kk++) {
        float4 w = *(const float4*)(wlds + (k + kk) * H + lane * 4);
#pragma unroll
        for (int i = 0; i < 6; i++) fma4(a[i], f4_at(xv[i], kk), w);
      }
    }
  }
}

__device__ __forceinline__ void write_tile(float* __restrict__ Y, int t, int lane,
    float4* a) {
  int n0 = t * 6;
  int nv = min(6, NN - n0);
  float* y = Y + (size_t)n0 * H + lane * 4;
#pragma unroll
  for (int i = 0; i < 6; i++) {
    if (i < nv) *(float4*)(y + (size_t)i * H) = relu4(a[i]);
  }
}

// ---------------------------------------------------------------- input-layer GEMM (K=64)
// 32KB LDS -> 4 blocks/CU, 1024 blocks, one 4-node tile per group (R8, kept).
__global__ __launch_bounds__(512) void k_gemm64(const float* __restrict__ X,
    const float* __restrict__ Wt, const float* __restrict__ bias,
    float* __restrict__ Y) {
  __shared__ float wlds[INF * H];
#pragma unroll
  for (int i = 0; i < 4; i++) {
    int idx = (threadIdx.x + i * 512) * 4;
    *(float4*)(wlds + idx) = *(const float4*)(Wt + idx);
  }
  __syncthreads();
  const int lane = threadIdx.x & 31;
  const int g = (threadIdx.x >> 5) * gridDim.x + blockIdx.x;
  const int n0 = g * 4;
  if (n0 >= NN) return;
  const int nv = min(4, NN - n0);
  float4 bb = *(const float4*)(bias + lane * 4);
  float4 a[4];
#pragma unroll
  for (int i = 0; i < 4; i++) a[i] = bb;
  const float* x0 = X + (size_t)n0 * INF;
  if (nv == 4) {
    for (int k = 0; k < INF; k += 4) {
      float4 xv[4];
#pragma unroll
      for (int i = 0; i < 4; i++)
        xv[i] = *(const float4*)(x0 + (size_t)i * INF + k);
#pragma unroll
      for (int kk = 0; kk < 4; kk++) {
        float4 w = *(const float4*)(wlds + (k + kk) * H + lane * 4);
#pragma unroll
        for (int i = 0; i < 4; i++) fma4(a[i], f4_at(xv[i], kk), w);
      }
    }
  } else {
    for (int k = 0; k < INF; k += 4) {
      float4 xv[4];
#pragma unroll
      for (int i = 0; i < 4; i++)
        xv[i] = (i < nv) ? *(const float4*)(x0 + (size_t)i * INF + k)
                         : make_float4(0.f, 0.f, 0.f, 0.f);
#pragma unroll
      for (int kk = 0; kk < 4; kk++) {
        float4 w = *(const float4*)(wlds + (k + kk) * H + lane * 4);
#pragma unroll
        for (int i = 0; i < 4; i++) fma4(a[i], f4_at(xv[i], kk), w);
      }
    }
  }
  float* y = Y + (size_t)n0 * H + lane * 4;
#pragma unroll
  for (int i = 0; i < 4; i++)
    if (i < nv) *(float4*)(y + (size_t)i * H) = relu4(a[i]);
}

// ---------------------------------------------------------------- hidden GEMM (K=128)
// R7 grid-stride 6-node map (empirically best) + prefetch-1 accum.
__global__ __launch_bounds__(512) void k_gemmH(const float* __restrict__ X,
    const float* __restrict__ Wt, const float* __restrict__ bias,
    float* __restrict__ Y) {
  __shared__ float wlds[H * H];
#pragma unroll
  for (int i = 0; i < 8; i++) {
    int idx = (threadIdx.x + i * 512) * 4;
    *(float4*)(wlds + idx) = *(const float4*)(Wt + idx);
  }
  __syncthreads();
  const int lane = threadIdx.x & 31;
  float4 bb = *(const float4*)(bias + lane * 4);
  const int NT = (NN + 5) / 6;
  const int g0 = (threadIdx.x >> 5) * gridDim.x + blockIdx.x;
  const int stride = gridDim.x * 16;
  for (int t = g0; t < NT; t += stride) {
    float4 a[6];
#pragma unroll
    for (int i = 0; i < 6; i++) a[i] = bb;
    accum_tile(X, t, wlds, lane, a);
    write_tile(Y, t, lane, a);
  }
}

// ---------------------------------------------------------------- fused 3-phase conv GEMM
// R7 two-tile form + prefetch-1. Y written once.
__global__ __launch_bounds__(512) void k_lin3f(const float* __restrict__ X0,
    const float* __restrict__ X1, const float* __restrict__ X2,
    const float* __restrict__ A, const float* __restrict__ B,
    const float* __restrict__ C, const float* __restrict__ bias,
    float* __restrict__ Y) {
  __shared__ float wlds[H * H];
  const int lane = threadIdx.x & 31;
  const int g0 = (threadIdx.x >> 5) * gridDim.x + blockIdx.x;
  const int NG = gridDim.x * 16;       // 8192 groups
  const int NT = (NN + 5) / 6;         // 8334 tiles
  const int t0 = g0, t1 = g0 + NG;
  float4 bb = *(const float4*)(bias + lane * 4);
  float4 a0[6], a1[6];
#pragma unroll
  for (int i = 0; i < 6; i++) { a0[i] = bb; a1[i] = bb; }

#define PHASE(W, X)                                                      \
  {                                                                      \
    __syncthreads();                                                     \
    _Pragma("unroll")                                                    \
    for (int i = 0; i < 8; i++) {                                        \
      int idx = (threadIdx.x + i * 512) * 4;                             \
      *(float4*)(wlds + idx) = *(const float4*)((W) + idx);              \
    }                                                                    \
    __syncthreads();                                                     \
    accum_tile((X), t0, wlds, lane, a0);                                 \
    if (t1 < NT) accum_tile((X), t1, wlds, lane, a1);                    \
  }

  PHASE(A, X0)
  PHASE(B, X1)
  PHASE(C, X2)
#undef PHASE

  write_tile(Y, t0, lane, a0);
  if (t1 < NT) write_tile(Y, t1, lane, a1);
}

// ---------------------------------------------------------------- attention (R7 form)
__global__ __launch_bounds__(512) void k_attn(const float* __restrict__ Ho,
    const float* __restrict__ Hk, const float* __restrict__ Wa1t,
    const float* __restrict__ ba1, const float* __restrict__ Wa2,
    float* __restrict__ sums) {
  __shared__ float wlds[H * H];
#pragma unroll
  for (int i = 0; i < 8; i++) {
    int idx = (threadIdx.x + i * 512) * 4;
    *(float4*)(wlds + idx) = *(const float4*)(Wa1t + idx);
  }
  __syncthreads();
  const int lane = threadIdx.x & 31;
  float4 bb = *(const float4*)(ba1 + lane * 4);
  float4 w2 = *(const float4*)(Wa2 + lane * 4);
  const int g0 = (threadIdx.x >> 5) * gridDim.x + blockIdx.x;
  const int stride = gridDim.x * 16;
  float po = 0.f, pk = 0.f;
  for (int t = g0; t < NN / 4; t += stride) {
    int n0 = t * 4;
    const float* ho = Ho + (size_t)n0 * H;
    const float* hk = Hk + (size_t)n0 * H;
    float4 ao[4], ak[4];
#pragma unroll
    for (int i = 0; i < 4; i++) { ao[i] = bb; ak[i] = bb; }
    for (int k = 0; k < H; k += 4) {
      float4 xo[4], xk[4];
#pragma unroll
      for (int i = 0; i < 4; i++) {
        xo[i] = *(const float4*)(ho + (size_t)i * H + k);
        xk[i] = *(const float4*)(hk + (size_t)i * H + k);
      }
#pragma unroll
      for (int kk = 0; kk < 4; kk++) {
        float4 w = *(const float4*)(wlds + (k + kk) * H + lane * 4);
#pragma unroll
        for (int i = 0; i < 4; i++) {
          fma4(ao[i], f4_at(xo[i], kk), w);
          fma4(ak[i], f4_at(xk[i], kk), w);
        }
      }
    }
#pragma unroll
    for (int i = 0; i < 4; i++) {
      po += dot_tanh4(w2, ao[i]);
      pk += dot_tanh4(w2, ak[i]);
    }
  }
  for (int d = 32; d > 0; d >>= 1) {
    po += __shfl_down(po, d, 64);
    pk += __shfl_down(pk, d, 64);
  }
  __syncthreads();  // all weight reads done; safe to reuse wlds
  int wv = threadIdx.x >> 6;
  if ((threadIdx.x & 63) == 0) { wlds[wv] = po; wlds[8 + wv] = pk; }
  __syncthreads();
  if (threadIdx.x == 0) {
    float so = 0.f, sk = 0.f;
    for (int i = 0; i < 8; i++) { so += wlds[i]; sk += wlds[8 + i]; }
    atomicAdd(&sums[0], so);
    atomicAdd(&sums[1], sk);
  }
}

// ---------------------------------------------------------------- SpMM (unroll-8)
__global__ __launch_bounds__(256) void k_spmm(const float* __restrict__ X,
    const float* __restrict__ dinv, const int* __restrict__ rp,
    const int* __restrict__ adj, float* __restrict__ Y) {
  int g = blockIdx.x * blockDim.x + threadIdx.x;
  int n = g >> 5, lane = g & 31;
  if (n >= NN) return;
  float4 acc = make_float4(0.f, 0.f, 0.f, 0.f);
  int beg = rp[n], end = rp[n + 1];
  const float* Xl = X + lane * 4;
  int e = beg;
  for (; e + 8 <= end; e += 8) {
    int s[8];
#pragma unroll
    for (int j = 0; j < 8; j++) s[j] = adj[e + j];
    float d[8];
#pragma unroll
    for (int j = 0; j < 8; j++) d[j] = dinv[s[j]];
    float4 v[8];
#pragma unroll
    for (int j = 0; j < 8; j++) v[j] = *(const float4*)(Xl + (size_t)s[j] * H);
#pragma unroll
    for (int j = 0; j < 8; j++) fma4(acc, d[j], v[j]);
  }
  for (; e + 4 <= end; e += 4) {
    int s0 = adj[e], s1 = adj[e + 1], s2 = adj[e + 2], s3 = adj[e + 3];
    float d0 = dinv[s0], d1 = dinv[s1], d2 = dinv[s2], d3 = dinv[s3];
    float4 v0 = *(const float4*)(Xl + (size_t)s0 * H);
    float4 v1 = *(const float4*)(Xl + (size_t)s1 * H);
    float4 v2 = *(const float4*)(Xl + (size_t)s2 * H);
    float4 v3 = *(const float4*)(Xl + (size_t)s3 * H);
    fma4(acc, d0, v0);
    fma4(acc, d1, v1);
    fma4(acc, d2, v2);
    fma4(acc, d3, v3);
  }
  for (; e < end; e++) {
    int s = adj[e];
    fma4(acc, dinv[s], *(const float4*)(Xl + (size_t)s * H));
  }
  float dn = dinv[n];
  acc.x *= dn; acc.y *= dn; acc.z *= dn; acc.w *= dn;
  *(float4*)(Y + (size_t)n * H + lane * 4) = acc;
}

// ---------------------------------------------------------------- final: beta-blend + classifier
__global__ __launch_bounds__(256) void k_final(const float* __restrict__ Ho,
    const float* __restrict__ Hk, const float* __restrict__ sums,
    const float* __restrict__ W4, const float* __restrict__ b4,
    float* __restrict__ out) {
  int g = blockIdx.x * blockDim.x + threadIdx.x;
  int n = g >> 5, lane = g & 31;
  if (n >= NN) return;
  float mo = sums[0] * (1.f / NN);
  float mk = sums[1] * (1.f / NN);
  float mx = fmaxf(mo, mk);
  float eo = __expf(mo - mx), ek = __expf(mk - mx);
  float inv = 1.f / (eo + ek);
  float bo = eo * inv, bk2 = ek * inv;
  float4 ho = *(const float4*)(Ho + (size_t)n * H + lane * 4);
  float4 hk = *(const float4*)(Hk + (size_t)n * H + lane * 4);
  float4 emb;
  emb.x = bo * ho.x + bk2 * hk.x;
  emb.y = bo * ho.y + bk2 * hk.y;
  emb.z = bo * ho.z + bk2 * hk.z;
  emb.w = bo * ho.w + bk2 * hk.w;
  *(float4*)(out + 2 * NN + (size_t)n * H + lane * 4) = emb;
  float4 w0 = *(const float4*)(W4 + lane * 4);
  float4 w1 = *(const float4*)(W4 + H + lane * 4);
  float p0 = emb.x * w0.x + emb.y * w0.y + emb.z * w0.z + emb.w * w0.w;
  float p1 = emb.x * w1.x + emb.y * w1.y + emb.z * w1.z + emb.w * w1.w;
  for (int d = 16; d > 0; d >>= 1) {
    p0 += __shfl_down(p0, d, 32);
    p1 += __shfl_down(p1, d, 32);
  }
  if (lane == 0) {
    out[n * 2 + 0] = p0 + b4[0];
    out[n * 2 + 1] = p1 + b4[1];
  }
}

// ================================================================ host
extern "C" void kernel_launch(void* const* d_in, const int* in_sizes, int n_in,
                              void* d_out, int out_size, void* d_ws, size_t ws_size,
                              hipStream_t stream) {
  const float* x      = (const float*)d_in[0];
  const int*   src_g  = (const int*)d_in[1];
  const int*   dst_g  = (const int*)d_in[2];
  const int*   src_k  = (const int*)d_in[3];
  const int*   dst_k  = (const int*)d_in[4];
  const float* W1     = (const float*)d_in[5];
  const float* b1     = (const float*)d_in[6];
  const float* W2     = (const float*)d_in[7];
  const float* b2     = (const float*)d_in[8];
  const float* diag_g = (const float*)d_in[9];
  const float* Wc_g   = (const float*)d_in[10];
  const float* bc_g   = (const float*)d_in[11];
  const float* diag_k = (const float*)d_in[12];
  const float* Wc_k   = (const float*)d_in[13];
  const float* bc_k   = (const float*)d_in[14];
  const float* W3     = (const float*)d_in[15];
  const float* b3     = (const float*)d_in[16];
  const float* Wk     = (const float*)d_in[17];
  const float* bk     = (const float*)d_in[18];
  const float* Wa1    = (const float*)d_in[19];
  const float* ba1    = (const float*)d_in[20];
  const float* Wa2    = (const float*)d_in[21];
  const float* W4     = (const float*)d_in[22];
  const float* b4     = (const float*)d_in[23];
  float* out = (float*)d_out;

  // ---- workspace bump allocator (256B aligned)
  char* base = (char*)d_ws;
  size_t off = 0;
  auto alloc = [&](size_t bytes) -> char* {
    char* r = base + off;
    off = (off + bytes + 255) & ~(size_t)255;
    return r;
  };
  // zero region (memset each launch): bucket counters + sums
  int* bcnt_g = (int*)alloc(256 * 4);
  int* bcnt_k = (int*)alloc(256 * 4);
  float* sums = (float*)alloc(256);
  size_t zero_bytes = off;

  int* bbase_g = (int*)alloc((NB + 1) * 4);
  int* bbase_k = (int*)alloc((NB + 1) * 4);
  int* bcur_g  = (int*)alloc(NB * 4);
  int* bcur_k  = (int*)alloc(NB * 4);
  int* rp_g    = (int*)alloc((NN + 1) * 4);
  int* rp_k    = (int*)alloc((NN + 1) * 4);
  int2* ebuf_g = (int2*)alloc((size_t)EG * 8);
  int2* ebuf_k = (int2*)alloc((size_t)EK * 8);
  int* adj_g   = (int*)alloc(EG * 4);
  int* adj_k   = (int*)alloc(EK * 4);
  float* dinv_g = (float*)alloc(NN * 4);
  float* dinv_k = (float*)alloc(NN * 4);
  float* Wt1  = (float*)alloc(INF * H * 4);
  float* Wt2  = (float*)alloc(H * H * 4);
  float* Wa1t = (float*)alloc(H * H * 4);
  float* Ag = (float*)alloc(H * H * 4);
  float* Bg = (float*)alloc(H * H * 4);
  float* Cg = (float*)alloc(H * H * 4);
  float* biasg = (float*)alloc(H * 4);
  float* Ak = (float*)alloc(H * H * 4);
  float* Bk = (float*)alloc(H * H * 4);
  float* Ck = (float*)alloc(H * H * 4);
  float* biask = (float*)alloc(H * 4);
  float* B0 = (float*)alloc((size_t)NN * H * 4);  // t1, later h_o
  float* B1 = (float*)alloc((size_t)NN * H * 4);  // h
  float* B2 = (float*)alloc((size_t)NN * H * 4);  // u
  float* B3 = (float*)alloc((size_t)NN * H * 4);  // w
  float* B4 = (float*)alloc((size_t)NN * H * 4);  // h_knn
  (void)ws_size; (void)in_sizes; (void)n_in; (void)out_size;

  hipMemsetAsync(d_ws, 0, zero_bytes, stream);

  const int GB = NN * 32 / 256;  // 1 node / 32 threads (spmm, final)

  // CSR build v2: hist -> scan -> partition -> per-bucket CSR (+dinv)
  k_hist<<<512, 256, 0, stream>>>(dst_g, dst_k, bcnt_g, bcnt_k);
  k_bscan<<<1, 256, 0, stream>>>(bcnt_g, bcnt_k, bbase_g, bbase_k,
                                 bcur_g, bcur_k, rp_g, rp_k);
  k_part<EG><<<512, 256, 0, stream>>>(src_g, dst_g, bcur_g, ebuf_g);
  k_part<EK><<<512, 256, 0, stream>>>(src_k, dst_k, bcur_k, ebuf_k);
  k_bcsr<<<NB, 256, 0, stream>>>(ebuf_g, bbase_g, rp_g, adj_g, dinv_g);
  k_bcsr<<<NB, 256, 0, stream>>>(ebuf_k, bbase_k, rp_k, adj_k, dinv_k);

  // weight prep
  k_transpose<<<(H * INF + 255) / 256, 256, 0, stream>>>(W1, Wt1, H, INF);
  k_transpose<<<(H * H + 255) / 256, 256, 0, stream>>>(W2, Wt2, H, H);
  k_transpose<<<(H * H + 255) / 256, 256, 0, stream>>>(Wa1, Wa1t, H, H);
  Theta9 thG = {{3.f, -3.f, 0.75f, 0.f, 3.f, -1.5f, 0.f, 0.f, 0.75f}};
  Theta9 thK = {{1.f, 1.f, 1.f, 1.f, 1.f, 1.f, 1.f, 1.f, 1.f}};
  k_genmat<<<64, 256, 0, stream>>>(diag_g, Wc_g, W3, thG, Ag, Bg, Cg);
  k_genmat<<<64, 256, 0, stream>>>(diag_k, Wc_k, Wk, thK, Ak, Bk, Ck);
  k_genbias<<<1, 128, 0, stream>>>(bc_g, W3, b3, biasg);
  k_genbias<<<1, 128, 0, stream>>>(bc_k, Wk, bk, biask);

  // input MLP
  k_gemm64<<<1024, 512, 0, stream>>>(x, Wt1, b1, B0);   // t1
  k_gemmH<<<GRID, 512, 0, stream>>>(B0, Wt2, b2, B1);   // h

  // graph G: u, w, fused conv+fusion (single 3-phase GEMM)
  k_spmm<<<GB, 256, 0, stream>>>(B1, dinv_g, rp_g, adj_g, B2);  // u_g
  k_spmm<<<GB, 256, 0, stream>>>(B2, dinv_g, rp_g, adj_g, B3);  // w_g
  k_lin3f<<<GRID, 512, 0, stream>>>(B1, B2, B3, Ag, Bg, Cg, biasg, B0);  // h_o

  // graph K
  k_spmm<<<GB, 256, 0, stream>>>(B1, dinv_k, rp_k, adj_k, B2);  // u_k
  k_spmm<<<GB, 256, 0, stream>>>(B2, dinv_k, rp_k, adj_k, B3);  // w_k
  k_lin3f<<<GRID, 512, 0, stream>>>(B1, B2, B3, Ak, Bk, Ck, biask, B4);  // h_knn

  // attention + output
  k_attn<<<GRID, 512, 0, stream>>>(B0, B4, Wa1t, ba1, Wa2, sums);
  k_final<<<GB, 256, 0, stream>>>(B0, B4, sums, W4, b4, out);
}